// Round 1
// baseline (1316.142 us; speedup 1.0000x reference)
//
#include <hip/hip_runtime.h>

// Problem: x [1, 4096] f32, weights [512, 4096, 128] f32
// ret[o] = sum_{s,a} x[s] * w[o,s,a]
// Memory-bound: weights = 1 GiB streamed once. Target ~170 us @ 6.3 TB/s.

#define OUT_DIM 512
#define NS 4096
#define NA 128
#define SLICES 8                    // blocks per output row
#define BLOCK 256
// per-o elements = NS*NA = 524288 f32 = 131072 float4
// per-slice = 16384 float4 ; per-thread = 64 float4

__global__ __launch_bounds__(BLOCK) void lsh_reduce_kernel(
        const float* __restrict__ x,
        const float* __restrict__ w,
        float* __restrict__ out) {
    __shared__ float xs[NS];        // 16 KiB
    __shared__ float part[BLOCK / 64];

    // Stage x into LDS (vectorized, coalesced)
    const float4* x4 = (const float4*)x;
    for (int i = threadIdx.x; i < NS / 4; i += BLOCK) {
        float4 v = x4[i];
        xs[i * 4 + 0] = v.x;
        xs[i * 4 + 1] = v.y;
        xs[i * 4 + 2] = v.z;
        xs[i * 4 + 3] = v.w;
    }
    __syncthreads();

    const int o     = blockIdx.x >> 3;      // / SLICES
    const int slice = blockIdx.x & (SLICES - 1);
    const float4* w4 = (const float4*)(w + (size_t)o * (NS * NA));
    const int base = slice * 16384;         // float4 units

    float acc = 0.0f;
    // 64 iterations, stride BLOCK float4 = 4 KiB -> fully coalesced stream
    #pragma unroll 8
    for (int i = 0; i < 64; ++i) {
        const int idx4 = base + i * BLOCK + (int)threadIdx.x;
        float4 v = w4[idx4];
        // NA=128 divisible by 4: all 4 elements of an aligned float4 share s
        const int s = idx4 >> 5;            // 32 float4 per sample row
        acc += (v.x + v.y + v.z + v.w) * xs[s];
    }

    // wave(64)-level shuffle reduction
    #pragma unroll
    for (int off = 32; off > 0; off >>= 1)
        acc += __shfl_down(acc, off, 64);

    const int lane = threadIdx.x & 63;
    const int wave = threadIdx.x >> 6;
    if (lane == 0) part[wave] = acc;
    __syncthreads();
    if (threadIdx.x == 0) {
        float t = part[0] + part[1] + part[2] + part[3];
        atomicAdd(out + o, t);              // 8 adds per output, negligible
    }
}

__global__ void lsh_zero_out(float* __restrict__ out) {
    out[blockIdx.x * BLOCK + threadIdx.x] = 0.0f;
}

extern "C" void kernel_launch(void* const* d_in, const int* in_sizes, int n_in,
                              void* d_out, int out_size, void* d_ws, size_t ws_size,
                              hipStream_t stream) {
    const float* x = (const float*)d_in[0];
    const float* w = (const float*)d_in[1];
    float* out = (float*)d_out;

    // d_out is poisoned (0xAA) before every timed launch -> zero it first
    lsh_zero_out<<<OUT_DIM / BLOCK, BLOCK, 0, stream>>>(out);
    lsh_reduce_kernel<<<OUT_DIM * SLICES, BLOCK, 0, stream>>>(x, w, out);
}